// Round 4
// baseline (983.785 us; speedup 1.0000x reference)
//
#include <hip/hip_runtime.h>

// Cost volume: out[b, dy*9+dx, h, w] = leaky( mean_c c1[b,c,h,w] * warped[b,c,h+dy-4,w+dx-4] )
// B=8 C=192 H=128 W=160, 81 offsets, fp32, zero-padded borders.
//
// R4: no LDS, no barriers. R3 post-mortem: barrier'd producer/consumer left
// >80% of wall time with ALL waves parked (VALUBusy 17%, occ 17.6%). Per-chunk
// working set (26KB) fits L1, so LDS staging buys nothing. Each thread owns a
// 9dx x 8w tile for one (h,dy); warped window loads go straight to registers.
// Zero-padding: window [w0-4, w0+12) splits into 4 float4s whose validity is
// loop-invariant (col edges hit float4 boundaries exactly; row validity is
// per-thread). Invalid pointers aim at a zero-filled __device__ array with
// stride 0 -> branchless, divergence-free inner loop: 6 loads + 72 FMAs per
// channel, register-prefetched one channel ahead. 192 channels, stride HW.
// Block = 384 thr (2 h-rows, 360 active), grid 512, blockIdx%8==b per-XCD.

namespace {
constexpr int SR   = 4;
constexpr int MO   = 9;
constexpr int NB   = 8;
constexpr int NC   = 192;
constexpr int NH   = 128;
constexpr int NW   = 160;
constexpr int HW   = NH * NW;
constexpr int NT   = 384;
constexpr int WPT  = 8;
}

__device__ __attribute__((aligned(64))) float g_zero[32];  // zero-initialized

__global__ __launch_bounds__(NT, 3)
void costvol_kernel(const float* __restrict__ c1,
                    const float* __restrict__ warped,
                    const float* __restrict__ alphap,
                    float* __restrict__ out)
{
    const int bi  = blockIdx.x;
    const int b   = bi & (NB - 1);       // %8 -> XCD-pinned batch
    const int h0  = (bi >> 3) * 2;
    const int tid = threadIdx.x;

    const int hh  = tid / 180;
    const int rem = tid - hh * 180;
    const int dy  = rem / 20;
    const int g   = rem - dy * 20;
    const int w0  = g * WPT;
    const bool active = tid < 360;

    const int h  = h0 + hh;
    const int hr = h + dy - SR;
    const bool hvalid = active && ((unsigned)hr < (unsigned)NH);

    const size_t baseB = (size_t)b * NC * HW;

    // 4 window-float4 pointers; invalid ones park on g_zero with stride 0.
    const float* wp0; const float* wp1; const float* wp2; const float* wp3;
    int s0, s1, s2, s3;
    {
        const float* rowp = warped + baseB + (size_t)hr * NW;
        const bool v0 = hvalid && (g > 0);    // cols w0-4..w0-1
        const bool v1 = hvalid;               // cols w0..w0+3   (always in-range)
        const bool v2 = hvalid;               // cols w0+4..w0+7
        const bool v3 = hvalid && (g < 19);   // cols w0+8..w0+11
        wp0 = v0 ? (rowp + (w0 - 4)) : g_zero;  s0 = v0 ? HW : 0;
        wp1 = v1 ? (rowp + (w0    )) : g_zero;  s1 = v1 ? HW : 0;
        wp2 = v2 ? (rowp + (w0 + 4)) : g_zero;  s2 = v2 ? HW : 0;
        wp3 = v3 ? (rowp + (w0 + 8)) : g_zero;  s3 = v3 ? HW : 0;
    }
    const float* cp = active ? (c1 + baseB + (size_t)h * NW + w0) : g_zero;
    const int    sc = active ? HW : 0;

    float acc[MO][WPT];
#pragma unroll
    for (int i = 0; i < MO; ++i)
#pragma unroll
        for (int j = 0; j < WPT; ++j) acc[i][j] = 0.0f;

    // prefetch channel 0
    float4 u0 = *(const float4*)wp0;  wp0 += s0;
    float4 u1 = *(const float4*)wp1;  wp1 += s1;
    float4 u2 = *(const float4*)wp2;  wp2 += s2;
    float4 u3 = *(const float4*)wp3;  wp3 += s3;
    float4 a0 = *(const float4*)cp;
    float4 a1 = *(const float4*)(cp + 4);  cp += sc;

#pragma unroll 2
    for (int c = 0; c < NC - 1; ++c) {
        const float4 v0 = u0, v1 = u1, v2 = u2, v3 = u3;
        const float4 b0 = a0, b1 = a1;
        // prefetch channel c+1 (independent of the FMA block below)
        u0 = *(const float4*)wp0;  wp0 += s0;
        u1 = *(const float4*)wp1;  wp1 += s1;
        u2 = *(const float4*)wp2;  wp2 += s2;
        u3 = *(const float4*)wp3;  wp3 += s3;
        a0 = *(const float4*)cp;
        a1 = *(const float4*)(cp + 4);  cp += sc;

        const float wn[16] = {v0.x, v0.y, v0.z, v0.w,  v1.x, v1.y, v1.z, v1.w,
                              v2.x, v2.y, v2.z, v2.w,  v3.x, v3.y, v3.z, v3.w};
        const float cv[WPT] = {b0.x, b0.y, b0.z, b0.w,  b1.x, b1.y, b1.z, b1.w};
#pragma unroll
        for (int dx = 0; dx < MO; ++dx)
#pragma unroll
            for (int j = 0; j < WPT; ++j)
                acc[dx][j] = fmaf(cv[j], wn[j + dx], acc[dx][j]);
    }
    {   // last channel
        const float wn[16] = {u0.x, u0.y, u0.z, u0.w,  u1.x, u1.y, u1.z, u1.w,
                              u2.x, u2.y, u2.z, u2.w,  u3.x, u3.y, u3.z, u3.w};
        const float cv[WPT] = {a0.x, a0.y, a0.z, a0.w,  a1.x, a1.y, a1.z, a1.w};
#pragma unroll
        for (int dx = 0; dx < MO; ++dx)
#pragma unroll
            for (int j = 0; j < WPT; ++j)
                acc[dx][j] = fmaf(cv[j], wn[j + dx], acc[dx][j]);
    }

    // epilogue: mean + leaky relu
    if (active) {
        const float scale = 1.0f / (float)NC;
        const float alpha = alphap[0];
        float* op = out + ((size_t)b * (MO * MO) + (size_t)(dy * MO)) * HW
                        + (size_t)h * NW + w0;
#pragma unroll
        for (int dx = 0; dx < MO; ++dx) {
            float r[WPT];
#pragma unroll
            for (int j = 0; j < WPT; ++j) {
                const float vv = acc[dx][j] * scale;
                r[j] = (vv >= 0.0f) ? vv : alpha * vv;
            }
            float4* q = (float4*)(op + (size_t)dx * HW);
            q[0] = make_float4(r[0], r[1], r[2], r[3]);
            q[1] = make_float4(r[4], r[5], r[6], r[7]);
        }
    }
}

extern "C" void kernel_launch(void* const* d_in, const int* in_sizes, int n_in,
                              void* d_out, int out_size, void* d_ws, size_t ws_size,
                              hipStream_t stream) {
    (void)in_sizes; (void)n_in; (void)out_size; (void)d_ws; (void)ws_size;
    const float* c1     = (const float*)d_in[0];
    const float* warped = (const float*)d_in[1];
    const float* alpha  = (const float*)d_in[2];
    float* out          = (float*)d_out;
    costvol_kernel<<<dim3(NB * NH / 2), dim3(NT), 0, stream>>>(c1, warped, alpha, out);
}